// Round 1
// baseline (77.472 us; speedup 1.0000x reference)
//
#include <hip/hip_runtime.h>
#include <cmath>

#define B_ 32
#define S_ 4096
#define E_ 512
#define H_ 1024

// ---------------------------------------------------------------------------
// Kernel 1: v_t[b,e] = tanhf(dot(h[b,:], W[e,:]) + bias[e])
// One wave per output element; lane reads 16 contiguous f32 (4x float4).
// ---------------------------------------------------------------------------
__global__ __launch_bounds__(256) void vt_kernel(const float* __restrict__ h,
                                                 const float* __restrict__ W,
                                                 const float* __restrict__ bias,
                                                 float* __restrict__ vt) {
    int wid  = threadIdx.x >> 6;
    int lane = threadIdx.x & 63;
    int out  = blockIdx.x * 4 + wid;        // 0 .. B*E-1
    int b    = out >> 9;                    // / E_
    int e    = out & (E_ - 1);
    const float* hrow = h + b * H_;
    const float* wrow = W + (size_t)e * H_;
    int base = lane * 16;
    float acc = 0.f;
#pragma unroll
    for (int j = 0; j < 4; ++j) {
        float4 hv = *reinterpret_cast<const float4*>(hrow + base + j * 4);
        float4 wv = *reinterpret_cast<const float4*>(wrow + base + j * 4);
        acc += hv.x * wv.x + hv.y * wv.y + hv.z * wv.z + hv.w * wv.w;
    }
#pragma unroll
    for (int off = 32; off > 0; off >>= 1) acc += __shfl_xor(acc, off, 64);
    if (lane == 0) vt[out] = tanhf(acc + bias[e]);
}

// ---------------------------------------------------------------------------
// Kernel 2: fused gather + scores + online softmax + weighted accumulate.
// Block = 4 waves, each wave owns a strided subset of the chunk's s values.
// Per s: row = emb[mems[b,s]]; score = dot(row, v_t[b]); online-softmax
// update of (m, l, acc[512]) held as 8 f32/lane.
// Block-combines the 4 waves via LDS, writes partial {m, l, acc[E]} to ws.
// ---------------------------------------------------------------------------
__global__ __launch_bounds__(256) void attn_part_kernel(const int* __restrict__ mems,
                                                        const float* __restrict__ emb,
                                                        const float* __restrict__ vt,
                                                        float* __restrict__ partial,
                                                        int nchunk) {
    int b     = blockIdx.x / nchunk;
    int chunk = blockIdx.x % nchunk;
    int wid   = threadIdx.x >> 6;
    int lane  = threadIdx.x & 63;
    int rows_per_block = S_ / nchunk;
    int s0 = chunk * rows_per_block;

    // v_t fragment for this lane (elements lane*8 .. lane*8+7)
    const float* vrow = vt + (size_t)b * E_ + lane * 8;
    float4 v0 = *reinterpret_cast<const float4*>(vrow);
    float4 v1 = *reinterpret_cast<const float4*>(vrow + 4);

    float m = -1e30f, l = 0.f;
    float4 acc0 = {0.f, 0.f, 0.f, 0.f};
    float4 acc1 = {0.f, 0.f, 0.f, 0.f};

    const int* midx = mems + (size_t)b * S_;

    for (int s = s0 + wid; s < s0 + rows_per_block; s += 4) {
        int idx = midx[s];
        const float* row = emb + (size_t)idx * E_ + lane * 8;
        float4 r0 = *reinterpret_cast<const float4*>(row);
        float4 r1 = *reinterpret_cast<const float4*>(row + 4);
        float p = r0.x * v0.x + r0.y * v0.y + r0.z * v0.z + r0.w * v0.w
                + r1.x * v1.x + r1.y * v1.y + r1.z * v1.z + r1.w * v1.w;
#pragma unroll
        for (int off = 32; off > 0; off >>= 1) p += __shfl_xor(p, off, 64);
        float m_new = fmaxf(m, p);
        float corr  = __expf(m - m_new);
        float w     = __expf(p - m_new);
        l = l * corr + w;
        acc0.x = acc0.x * corr + w * r0.x;
        acc0.y = acc0.y * corr + w * r0.y;
        acc0.z = acc0.z * corr + w * r0.z;
        acc0.w = acc0.w * corr + w * r0.w;
        acc1.x = acc1.x * corr + w * r1.x;
        acc1.y = acc1.y * corr + w * r1.y;
        acc1.z = acc1.z * corr + w * r1.z;
        acc1.w = acc1.w * corr + w * r1.w;
        m = m_new;
    }

    // --- block combine across the 4 waves ---
    __shared__ float s_m[4], s_l[4];
    __shared__ float s_acc[4][E_];
    if (lane == 0) { s_m[wid] = m; s_l[wid] = l; }
    float* dst = &s_acc[wid][lane * 8];
    reinterpret_cast<float4*>(dst)[0] = acc0;
    reinterpret_cast<float4*>(dst)[1] = acc1;
    __syncthreads();

    float mb = fmaxf(fmaxf(s_m[0], s_m[1]), fmaxf(s_m[2], s_m[3]));
    float f0 = __expf(s_m[0] - mb);
    float f1 = __expf(s_m[1] - mb);
    float f2 = __expf(s_m[2] - mb);
    float f3 = __expf(s_m[3] - mb);
    float lb = s_l[0] * f0 + s_l[1] * f1 + s_l[2] * f2 + s_l[3] * f3;

    float* base = partial + (size_t)(b * nchunk + chunk) * (E_ + 2);
    if (threadIdx.x == 0) { base[0] = mb; base[1] = lb; }
    for (int e = threadIdx.x; e < E_; e += 256) {
        base[2 + e] = s_acc[0][e] * f0 + s_acc[1][e] * f1
                    + s_acc[2][e] * f2 + s_acc[3][e] * f3;
    }
}

// ---------------------------------------------------------------------------
// Kernel 3: deterministic combine of nchunk partials per batch, normalize.
// ---------------------------------------------------------------------------
__global__ __launch_bounds__(256) void combine_kernel(const float* __restrict__ partial,
                                                      float* __restrict__ out,
                                                      int nchunk) {
    int b = blockIdx.x;
    const int P = E_ + 2;
    float m_g = -1e30f;
    for (int c = 0; c < nchunk; ++c)
        m_g = fmaxf(m_g, partial[(size_t)(b * nchunk + c) * P]);
    float L = 0.f;
    for (int c = 0; c < nchunk; ++c) {
        const float* p = partial + (size_t)(b * nchunk + c) * P;
        L += p[1] * __expf(p[0] - m_g);
    }
    float inv = 1.f / L;
    for (int e = threadIdx.x; e < E_; e += 256) {
        float s = 0.f;
        for (int c = 0; c < nchunk; ++c) {
            const float* p = partial + (size_t)(b * nchunk + c) * P;
            s += __expf(p[0] - m_g) * p[2 + e];
        }
        out[(size_t)b * E_ + e] = s * inv;
    }
}

extern "C" void kernel_launch(void* const* d_in, const int* in_sizes, int n_in,
                              void* d_out, int out_size, void* d_ws, size_t ws_size,
                              hipStream_t stream) {
    const float* h    = (const float*)d_in[0];   // [B,H]
    const int*   mems = (const int*)d_in[1];     // [B,S] (int32 on device)
    const float* emb  = (const float*)d_in[2];   // [V,E]
    const float* W    = (const float*)d_in[3];   // [E,H]
    const float* bias = (const float*)d_in[4];   // [E]
    float* out = (float*)d_out;                  // [B,1,E] -> B*E floats

    float* ws = (float*)d_ws;
    float* vt = ws;                              // B*E floats
    // partials start after vt
    int nchunk = 32;
    while (nchunk > 1 &&
           (size_t)(B_ * E_ + B_ * nchunk * (E_ + 2)) * sizeof(float) > ws_size) {
        nchunk >>= 1;
    }
    float* partial = ws + B_ * E_;

    hipLaunchKernelGGL(vt_kernel, dim3(B_ * E_ / 4), dim3(256), 0, stream,
                       h, W, bias, vt);
    hipLaunchKernelGGL(attn_part_kernel, dim3(B_ * nchunk), dim3(256), 0, stream,
                       mems, emb, vt, partial, nchunk);
    hipLaunchKernelGGL(combine_kernel, dim3(B_), dim3(256), 0, stream,
                       partial, out, nchunk);
}